// Round 2
// baseline (53.651 us; speedup 1.0000x reference)
//
#include <hip/hip_runtime.h>
#include <hip/hip_bf16.h>

typedef __bf16 bf16x8 __attribute__((ext_vector_type(8)));
typedef float f32x4 __attribute__((ext_vector_type(4)));

#define NB 8
#define NH 128
#define NWID 128
#define NC 32
#define NO 32
#define NPTS 9
#define KTOT 288   // 9*32
#define KPAD 296   // pad: row stride 148 words -> 2-way banks only
#define PB 64      // pixels per block

__global__ __launch_bounds__(256, 2)
void dcn_kernel(const float* __restrict__ x,
                const float* __restrict__ off,
                const float* __restrict__ Wsrc,
                const float* __restrict__ bias,
                float* __restrict__ out)
{
    __shared__ __hip_bfloat16 sMap[PB][KPAD];
    __shared__ __hip_bfloat16 sW[NO][KPAD];

    const int tid = threadIdx.x;

    // ---- stage W: W[n][c][o] -> sW[o][n*32+c] (bf16) ----
    for (int idx = tid; idx < NPTS * NC * NO; idx += 256) {
        int n = idx >> 10;        // /1024  (NC*NO)
        int r = idx & 1023;
        int c = r >> 5;
        int o = r & 31;
        sW[o][(n << 5) + c] = __float2bfloat16(Wsrc[idx]);
    }

    const int pix0 = blockIdx.x * PB;

    // ---- phase A: bilinear gather -> sMap (bf16) ----
    {
        const int cg  = tid & 15;   // channel-pair group: channels 2cg, 2cg+1
        const int grp = tid >> 4;   // 0..15
        // TF-quirk init_off: stack([ii,jj]).reshape(-1,2) pairs ACROSS the ii/jj boundary:
        // (0,0),(0,1),(1,1),(2,2),(2,0),(1,2),(0,1),(2,0),(1,2)
        const int ioff0[9] = {0,0,1,2,2,1,0,2,1};
        const int ioff1[9] = {0,1,1,2,0,2,1,0,2};
        #pragma unroll
        for (int pp = 0; pp < 4; ++pp) {
            const int lp = grp + (pp << 4);
            const int gp = pix0 + lp;
            const int bidx = gp >> 14;
            const int hh = (gp >> 7) & 127;
            const int ww = gp & 127;
            const float* xb = x + ((size_t)bidx << 19);   // b*128*128*32
            const float* offp = off + (size_t)gp * 18;
            #pragma unroll
            for (int n = 0; n < 9; ++n) {
                float o0 = offp[2 * n];
                float o1 = offp[2 * n + 1];
                float c0 = (float)(hh - 1 + ioff0[n]) + o0;
                float c1 = (float)(ww - 1 + ioff1[n]) + o1;
                c0 = fminf(fmaxf(c0, 0.f), 127.f);
                c1 = fminf(fmaxf(c1, 0.f), 127.f);
                float fl0 = floorf(c0), fl1 = floorf(c1);
                int lt0 = (int)fl0, lt1 = (int)fl1;
                int rb0 = (int)ceilf(c0), rb1 = (int)ceilf(c1);
                float f0 = c0 - fl0, f1 = c1 - fl1;
                const float2* r_lt = (const float2*)(xb + (size_t)((lt0 << 7) + lt1) * NC) + cg;
                const float2* r_rt = (const float2*)(xb + (size_t)((rb0 << 7) + lt1) * NC) + cg;
                const float2* r_lb = (const float2*)(xb + (size_t)((lt0 << 7) + rb1) * NC) + cg;
                const float2* r_rb = (const float2*)(xb + (size_t)((rb0 << 7) + rb1) * NC) + cg;
                float2 vlt = *r_lt;
                float2 vrt = *r_rt;
                float2 vlb = *r_lb;
                float2 vrb = *r_rb;
                // v_t = lerp(v_lt, v_rt, f0); v_b = lerp(v_lb, v_rb, f0); m = lerp(v_t, v_b, f1)
                float tx = vlt.x + (vrt.x - vlt.x) * f0;
                float ty = vlt.y + (vrt.y - vlt.y) * f0;
                float bx = vlb.x + (vrb.x - vlb.x) * f0;
                float by = vlb.y + (vrb.y - vlb.y) * f0;
                float mx = tx + (bx - tx) * f1;
                float my = ty + (by - ty) * f1;
                __hip_bfloat162 mp = __float22bfloat162_rn(make_float2(mx, my));
                *reinterpret_cast<__hip_bfloat162*>(&sMap[lp][(n << 5) + (cg << 1)]) = mp;
            }
        }
    }
    __syncthreads();

    // ---- phase B: (64px x 288) @ (288 x 32) via MFMA bf16 ----
    {
        const int wave = tid >> 6;          // 0..3 -> 16-pixel M-tile
        const int lane = tid & 63;
        const int mrow = (wave << 4) + (lane & 15);
        const int kq = (lane >> 4) << 3;    // 0,8,16,24
        f32x4 acc0 = {0.f, 0.f, 0.f, 0.f};
        f32x4 acc1 = {0.f, 0.f, 0.f, 0.f};
        #pragma unroll
        for (int ks = 0; ks < 9; ++ks) {
            const int k = (ks << 5) + kq;
            bf16x8 a  = *reinterpret_cast<const bf16x8*>(&sMap[mrow][k]);
            bf16x8 b0 = *reinterpret_cast<const bf16x8*>(&sW[lane & 15][k]);
            bf16x8 b1 = *reinterpret_cast<const bf16x8*>(&sW[(lane & 15) + 16][k]);
            acc0 = __builtin_amdgcn_mfma_f32_16x16x32_bf16(a, b0, acc0, 0, 0, 0);
            acc1 = __builtin_amdgcn_mfma_f32_16x16x32_bf16(a, b1, acc1, 0, 0, 0);
        }
        const int ocol = lane & 15;
        const float bias0 = bias[ocol];
        const float bias1 = bias[ocol + 16];
        const int rbase = (wave << 4) + ((lane >> 4) << 2);
        #pragma unroll
        for (int i = 0; i < 4; ++i) {
            const int gp = pix0 + rbase + i;
            float* op = out + (size_t)gp * NO;
            op[ocol]      = acc0[i] + bias0;
            op[ocol + 16] = acc1[i] + bias1;
        }
    }
}

extern "C" void kernel_launch(void* const* d_in, const int* in_sizes, int n_in,
                              void* d_out, int out_size, void* d_ws, size_t ws_size,
                              hipStream_t stream) {
    const float* x    = (const float*)d_in[0];
    const float* off  = (const float*)d_in[1];
    const float* Wsrc = (const float*)d_in[2];
    const float* bias = (const float*)d_in[3];
    float* out = (float*)d_out;
    const int npix = NB * NH * NWID;          // 131072
    dcn_kernel<<<npix / PB, 256, 0, stream>>>(x, off, Wsrc, bias, out);
}